// Round 6
// baseline (395.972 us; speedup 1.0000x reference)
//
#include <hip/hip_runtime.h>

#define N_BATCH 8192
#define S 14
#define N_CELLS (N_BATCH * S * S)

#define FPC 30
#define TILE 128                       // cells per tile (one wave, 2 cells/lane)
#define TILE_FLOATS (TILE * FPC)       // 3840 floats = 15360 B per tensor
#define CHUNK_FLOATS 256               // 64 lanes x 4 floats (16 B/lane DMA - verified width)
#define CHUNKS 15                      // 15360 B / 1024 B  (exact)
#define N_TILES (N_CELLS / TILE)       // 12544
#define GRID 512                       // persistent: 2 single-wave blocks per CU

typedef const __attribute__((address_space(1))) void gvoid;
typedef __attribute__((address_space(3))) void lvoid;

__global__ __launch_bounds__(64) void yolo_loss_kernel(
    const float* __restrict__ pred, const float* __restrict__ targ,
    float* __restrict__ out)
{
    // double-buffered: 2 tensors x 2 bufs x 15360 B = 61440 B (<= 64 KB static)
    __shared__ float sp[2][TILE_FLOATS];
    __shared__ float st[2][TILE_FLOATS];

    const int lane = threadIdx.x;   // 0..63
    float acc = 0.0f;

    // issue one tile's DMA: 15 chunks x 2 tensors = 30 vmcnt events, 16 B/lane.
    // LDS layout == global layout (dest = wave-uniform base + lane*16).
    auto issue_tile = [&](int tile, int buf) {
        const size_t base = (size_t)tile * TILE_FLOATS;
#pragma unroll
        for (int c = 0; c < CHUNKS; ++c) {
            const float* gp = pred + base + c * CHUNK_FLOATS + lane * 4;
            const float* gt = targ + base + c * CHUNK_FLOATS + lane * 4;
            __builtin_amdgcn_global_load_lds((gvoid*)gp, (lvoid*)&sp[buf][c * CHUNK_FLOATS], 16, 0, 0);
            __builtin_amdgcn_global_load_lds((gvoid*)gt, (lvoid*)&st[buf][c * CHUNK_FLOATS], 16, 0, 0);
        }
        // pin group boundaries: no DMA op may cross this point (vmcnt counting
        // relies on group-ordered issue; R5 failed because the prologue group
        // could interleave with the first in-loop group).
        asm volatile("" ::: "memory");
    };

    int tile = blockIdx.x;
    int buf = 0;
    issue_tile(tile, 0);                       // prologue: tile 0 -> buf 0

    while (true) {
        const int next = tile + GRID;
        const bool has_next = (next < N_TILES);   // wave-uniform

        if (has_next) {
            issue_tile(next, buf ^ 1);         // 30 new issues into other buffer
            // leave exactly the next tile's 30 in flight; current tile complete.
            asm volatile("s_waitcnt vmcnt(30)" ::: "memory");
        } else {
            asm volatile("s_waitcnt vmcnt(0)" ::: "memory");
        }

        // ---- compute 2 cells/lane from LDS (120 B lane stride, 8 B aligned) ----
#pragma unroll
        for (int half = 0; half < 2; ++half) {
            float p[FPC], t[FPC];
            const int cell = lane + half * 64;
            const float2* p2 = reinterpret_cast<const float2*>(&sp[buf][cell * FPC]);
            const float2* t2 = reinterpret_cast<const float2*>(&st[buf][cell * FPC]);
#pragma unroll
            for (int i = 0; i < 15; ++i) {
                float2 a = p2[i]; p[2 * i] = a.x; p[2 * i + 1] = a.y;
                float2 b = t2[i]; t[2 * i] = b.x; t[2 * i + 1] = b.y;
            }

            const float INV14 = 1.0f / 14.0f;
            const float objf = (t[4] > 0.0f) ? 1.0f : 0.0f;
            const float noof = 1.0f - objf;

            const float d4 = p[4] - t[4];
            const float d9 = p[9] - t[9];
            const float nooobj = noof * (d4 * d4 + d9 * d9);

            const float tx = t[0] * INV14, ty = t[1] * INV14;
            const float tw = t[2], th = t[3];
            const float tx1 = tx - 0.5f * tw, ty1 = ty - 0.5f * th;
            const float tx2 = tx + 0.5f * tw, ty2 = ty + 0.5f * th;
            const float area_t = (tx2 - tx1) * (ty2 - ty1);

            float iou[2];
#pragma unroll
            for (int b = 0; b < 2; ++b) {
                const float px = p[5 * b + 0] * INV14, py = p[5 * b + 1] * INV14;
                const float pw = p[5 * b + 2], ph = p[5 * b + 3];
                const float px1 = px - 0.5f * pw, py1 = py - 0.5f * ph;
                const float px2 = px + 0.5f * pw, py2 = py + 0.5f * ph;
                const float ltx = fmaxf(px1, tx1), lty = fmaxf(py1, ty1);
                const float rbx = fminf(px2, tx2), rby = fminf(py2, ty2);
                const float wx = fmaxf(rbx - ltx, 0.0f);
                const float wy = fmaxf(rby - lty, 0.0f);
                const float inter = wx * wy;
                const float area_p = (px2 - px1) * (py2 - py1);
                iou[b] = inter / (area_p + area_t - inter);
            }

            const int r = (iou[1] > iou[0]) ? 1 : 0;   // ties -> box 0 (jnp.argmax)
            const float max_iou = fmaxf(iou[0], iou[1]);

            const float pc = p[5 * r + 4];
            const float contain = objf * (pc - max_iou) * (pc - max_iou);
            const float pnc = p[5 * (1 - r) + 4];
            const float not_contain = objf * pnc * pnc;

            const float dx = p[5 * r + 0] - t[5 * r + 0];
            const float dy = p[5 * r + 1] - t[5 * r + 1];
            const float dw = sqrtf(p[5 * r + 2]) - sqrtf(t[5 * r + 2]);
            const float dh = sqrtf(p[5 * r + 3]) - sqrtf(t[5 * r + 3]);
            const float loc = objf * (dx * dx + dy * dy + dw * dw + dh * dh);

            float cls = 0.0f;
#pragma unroll
            for (int k = 10; k < 30; ++k) {
                const float d = p[k] - t[k];
                cls += d * d;
            }
            cls *= objf;

            acc += (5.0f * loc + 2.0f * contain + 0.5f * nooobj + cls + not_contain)
                 * (1.0f / (float)N_BATCH);
        }

        if (!has_next) break;
        buf ^= 1;
        tile = next;
    }

    // ---- 64-lane wave reduction -> one atomic per block (512 total) ----
#pragma unroll
    for (int off = 32; off > 0; off >>= 1)
        acc += __shfl_down(acc, off, 64);

    if (lane == 0)
        atomicAdd(out, acc);
}

extern "C" void kernel_launch(void* const* d_in, const int* in_sizes, int n_in,
                              void* d_out, int out_size, void* d_ws, size_t ws_size,
                              hipStream_t stream) {
    const float* pred = (const float*)d_in[0];
    const float* targ = (const float*)d_in[1];
    float* out = (float*)d_out;

    hipMemsetAsync(out, 0, sizeof(float), stream);

    yolo_loss_kernel<<<GRID, 64, 0, stream>>>(pred, targ, out);
}

// Round 7
// 384.067 us; speedup vs baseline: 1.0310x; 1.0310x over previous
//
#include <hip/hip_runtime.h>

#define N_BATCH 8192
#define S 14
#define N_CELLS (N_BATCH * S * S)

#define FPC 30
#define TILE 64                        // cells per tile (one wave)
#define TILE_FLOATS (TILE * FPC)       // 1920 floats = 7680 B per tensor
#define TILE_F2 (TILE_FLOATS / 2)      // 960 float2 per tensor
#define LPT 15                         // dwordx2 loads per tensor per lane (15*512B = 7680B)
#define N_TILES (N_CELLS / TILE)       // 25088
#define GRID 2560                      // 10 single-wave blocks per CU (LDS-limited)

__global__ __launch_bounds__(64) void yolo_loss_kernel(
    const float* __restrict__ pred, const float* __restrict__ targ,
    float* __restrict__ out)
{
    // single-buffered LDS (15360 B) -> 10 blocks/CU; registers are buffer #2
    __shared__ float sp[TILE_FLOATS];
    __shared__ float st[TILE_FLOATS];

    const int lane = threadIdx.x;   // 0..63
    float acc = 0.0f;

    const float2* predv = reinterpret_cast<const float2*>(pred);
    const float2* targv = reinterpret_cast<const float2*>(targ);
    float2* spv = reinterpret_cast<float2*>(sp);
    float2* stv = reinterpret_cast<float2*>(st);

    float2 rp[LPT], rt[LPT];   // staging registers: 2 x 15 x 8B = 240B/lane

    // coalesced issue: instruction c covers 512 contiguous bytes (8 B/lane)
    auto issue_loads = [&](int tile) {
        const size_t b = (size_t)tile * TILE_F2;
#pragma unroll
        for (int c = 0; c < LPT; ++c) {
            rp[c] = predv[b + c * 64 + lane];
            rt[c] = targv[b + c * 64 + lane];
        }
    };

    int tile = blockIdx.x;
    issue_loads(tile);                          // prologue

    while (true) {
        const int next = tile + GRID;
        const bool has_next = (next < N_TILES);    // wave-uniform

        // drain tile k's loads (compiler waitcnt) and park them in LDS
#pragma unroll
        for (int c = 0; c < LPT; ++c) {
            spv[c * 64 + lane] = rp[c];
            stv[c * 64 + lane] = rt[c];
        }

        // launch tile k+1's loads NOW so they fly during the compute phase
        if (has_next)
            issue_loads(next);
        asm volatile("" ::: "memory");   // pin: loads issue before compute's ds_reads

        // ---- compute tile k from LDS (stride 30 floats, 8 B aligned) ----
        {
            float p[FPC], t[FPC];
            const float2* p2 = reinterpret_cast<const float2*>(sp + lane * FPC);
            const float2* t2 = reinterpret_cast<const float2*>(st + lane * FPC);
#pragma unroll
            for (int i = 0; i < 15; ++i) {
                float2 a = p2[i]; p[2 * i] = a.x; p[2 * i + 1] = a.y;
                float2 b = t2[i]; t[2 * i] = b.x; t[2 * i + 1] = b.y;
            }

            const float INV14 = 1.0f / 14.0f;
            const float objf = (t[4] > 0.0f) ? 1.0f : 0.0f;
            const float noof = 1.0f - objf;

            const float d4 = p[4] - t[4];
            const float d9 = p[9] - t[9];
            const float nooobj = noof * (d4 * d4 + d9 * d9);

            const float tx = t[0] * INV14, ty = t[1] * INV14;
            const float tw = t[2], th = t[3];
            const float tx1 = tx - 0.5f * tw, ty1 = ty - 0.5f * th;
            const float tx2 = tx + 0.5f * tw, ty2 = ty + 0.5f * th;
            const float area_t = (tx2 - tx1) * (ty2 - ty1);

            float iou[2];
#pragma unroll
            for (int b = 0; b < 2; ++b) {
                const float px = p[5 * b + 0] * INV14, py = p[5 * b + 1] * INV14;
                const float pw = p[5 * b + 2], ph = p[5 * b + 3];
                const float px1 = px - 0.5f * pw, py1 = py - 0.5f * ph;
                const float px2 = px + 0.5f * pw, py2 = py + 0.5f * ph;
                const float ltx = fmaxf(px1, tx1), lty = fmaxf(py1, ty1);
                const float rbx = fminf(px2, tx2), rby = fminf(py2, ty2);
                const float wx = fmaxf(rbx - ltx, 0.0f);
                const float wy = fmaxf(rby - lty, 0.0f);
                const float inter = wx * wy;
                const float area_p = (px2 - px1) * (py2 - py1);
                iou[b] = inter / (area_p + area_t - inter);
            }

            const int r = (iou[1] > iou[0]) ? 1 : 0;   // ties -> box 0 (jnp.argmax)
            const float max_iou = fmaxf(iou[0], iou[1]);

            const float pc = p[5 * r + 4];
            const float contain = objf * (pc - max_iou) * (pc - max_iou);
            const float pnc = p[5 * (1 - r) + 4];
            const float not_contain = objf * pnc * pnc;

            const float dx = p[5 * r + 0] - t[5 * r + 0];
            const float dy = p[5 * r + 1] - t[5 * r + 1];
            const float dw = sqrtf(p[5 * r + 2]) - sqrtf(t[5 * r + 2]);
            const float dh = sqrtf(p[5 * r + 3]) - sqrtf(t[5 * r + 3]);
            const float loc = objf * (dx * dx + dy * dy + dw * dw + dh * dh);

            float cls = 0.0f;
#pragma unroll
            for (int k = 10; k < 30; ++k) {
                const float d = p[k] - t[k];
                cls += d * d;
            }
            cls *= objf;

            acc += (5.0f * loc + 2.0f * contain + 0.5f * nooobj + cls + not_contain)
                 * (1.0f / (float)N_BATCH);
        }

        if (!has_next) break;
        tile = next;
    }

    // ---- 64-lane wave reduction -> one atomic per block (2560 total) ----
#pragma unroll
    for (int off = 32; off > 0; off >>= 1)
        acc += __shfl_down(acc, off, 64);

    if (lane == 0)
        atomicAdd(out, acc);
}

extern "C" void kernel_launch(void* const* d_in, const int* in_sizes, int n_in,
                              void* d_out, int out_size, void* d_ws, size_t ws_size,
                              hipStream_t stream) {
    const float* pred = (const float*)d_in[0];
    const float* targ = (const float*)d_in[1];
    float* out = (float*)d_out;

    hipMemsetAsync(out, 0, sizeof(float), stream);

    yolo_loss_kernel<<<GRID, 64, 0, stream>>>(pred, targ, out);
}